// Round 1
// baseline (371.308 us; speedup 1.0000x reference)
//
#include <hip/hip_runtime.h>
#include <math.h>

#define D_    100
#define DM_   200
#define DI_   400
#define G4_   1600
#define NREL_ 5000
#define NB_   256
#define NN_   200
#define NSTEPS_ 4

__device__ __forceinline__ float sigf(float x){ return 1.0f/(1.0f+__expf(-x)); }

// ---------------------------------------------------------------------------
// Kernel 1: views.  grid = 1250 blocks (625 rel-groups + 625 ent-groups), 128 thr
// For rel rows: compute normalized views, reduce to scalar attention scores.
// For ent rows (0..4999 only): store normalized views.
#define VROWS 8
__global__ __launch_bounds__(128) void views_kernel(
    const float* __restrict__ ent_emb, const float* __restrict__ rel_emb,
    const float* __restrict__ W1, const float* __restrict__ b1,
    const float* __restrict__ W2, const float* __restrict__ b2,
    const float* __restrict__ W3, const float* __restrict__ b3,
    const float* __restrict__ attW1, const float* __restrict__ attW2,
    float* __restrict__ ent_v, float* __restrict__ rs_in, float* __restrict__ rs_out)
{
    int bid = blockIdx.x, tid = threadIdx.x;
    bool isRel = bid < 625;
    int row0 = (isRel ? bid : bid - 625) * VROWS;
    const float* src = isRel ? rel_emb : ent_emb;

    __shared__ float e[VROWS][D_];
    __shared__ float ys[VROWS][D_];
    __shared__ float invn[VROWS];

    for (int idx = tid; idx < VROWS*D_; idx += 128) (&e[0][0])[idx] = src[row0*D_ + idx];
    __syncthreads();

    const float* W[3]  = {W1, W2, W3};
    const float* bb[3] = {b1, b2, b3};

    #pragma unroll
    for (int v = 0; v < 3; ++v){
        float y[VROWS];
        if (tid < D_){
            float bv = bb[v][tid];
            #pragma unroll
            for (int r = 0; r < VROWS; ++r) y[r] = bv;
            const float* Wv = W[v];
            for (int i = 0; i < D_; ++i){
                float w = Wv[i*D_ + tid];
                #pragma unroll
                for (int r = 0; r < VROWS; ++r) y[r] += e[r][i] * w;
            }
            #pragma unroll
            for (int r = 0; r < VROWS; ++r) ys[r][tid] = y[r];
        }
        __syncthreads();
        if (tid < VROWS){
            float s = 0.f;
            for (int j = 0; j < D_; ++j){ float t = ys[tid][j]; s += t*t; }
            invn[tid] = 1.f / fmaxf(sqrtf(s), 1e-12f);
        }
        __syncthreads();
        if (isRel){
            if (tid < VROWS){
                float inv = invn[tid], s1 = 0.f, s2 = 0.f;
                for (int j = 0; j < D_; ++j){
                    float t = ys[tid][j] * inv;
                    s1 += t * attW1[j];
                    s2 += t * attW2[j];
                }
                rs_in [(row0+tid)*3 + v] = s1;
                rs_out[(row0+tid)*3 + v] = s2;
            }
        } else {
            if (tid < D_){
                #pragma unroll
                for (int r = 0; r < VROWS; ++r)
                    ent_v[(((long)(row0+r))*3 + v)*D_ + tid] = y[r] * invn[r];
            }
        }
        __syncthreads();
    }
}

// ---------------------------------------------------------------------------
// Kernel 2: neigh.  grid = 518 (256 ql + 256 qr + 3 sl + 3 sr), 256 thr.
// a = softmax_k(rs[c[k,0]][v]); h = sum_k a * ent_v[c[k,1]][v]; combine in/out.
__global__ __launch_bounds__(256) void neigh_kernel(
    const int* __restrict__ qlc_out, const int* __restrict__ qlc_in,
    const int* __restrict__ qrc_out, const int* __restrict__ qrc_in,
    const int* __restrict__ slc_out, const int* __restrict__ slc_in,
    const int* __restrict__ src_out, const int* __restrict__ src_in,
    const float* __restrict__ ent_v, const float* __restrict__ rs_in,
    const float* __restrict__ rs_out,
    float* __restrict__ qn, float* __restrict__ sn)
{
    int b = blockIdx.x, tid = threadIdx.x;
    const int *cin, *cout; float* dst;
    if      (b < 256){ int n=b;     cout=qlc_out+n*NN_*2; cin=qlc_in+n*NN_*2; dst=qn+n*600;      }
    else if (b < 512){ int n=b-256; cout=qrc_out+n*NN_*2; cin=qrc_in+n*NN_*2; dst=qn+n*600+100;  }
    else if (b < 515){ int n=b-512; cout=slc_out+n*NN_*2; cin=slc_in+n*NN_*2; dst=sn+n*600;      }
    else             { int n=b-515; cout=src_out+n*NN_*2; cin=src_in+n*NN_*2; dst=sn+n*600+100;  }

    __shared__ int irel[NN_], ient[NN_], orel[NN_], oent[NN_];
    __shared__ float ain[NN_], aout[NN_];
    __shared__ float red[256];
    __shared__ float hof[D_];

    if (tid < NN_){
        irel[tid]=cin [tid*2]; ient[tid]=cin [tid*2+1];
        orel[tid]=cout[tid*2]; oent[tid]=cout[tid*2+1];
    }
    __syncthreads();

    for (int v = 0; v < 3; ++v){
        float si = (tid<NN_) ? rs_in [irel[tid]*3+v] : -1e30f;
        float so = (tid<NN_) ? rs_out[orel[tid]*3+v] : -1e30f;

        red[tid]=si; __syncthreads();
        for (int s=128;s>0;s>>=1){ if(tid<s) red[tid]=fmaxf(red[tid],red[tid+s]); __syncthreads(); }
        float mi = red[0]; __syncthreads();
        red[tid]=so; __syncthreads();
        for (int s=128;s>0;s>>=1){ if(tid<s) red[tid]=fmaxf(red[tid],red[tid+s]); __syncthreads(); }
        float mo = red[0]; __syncthreads();

        float ei = (tid<NN_) ? __expf(si-mi) : 0.f;
        float eo = (tid<NN_) ? __expf(so-mo) : 0.f;
        red[tid]=ei; __syncthreads();
        for (int s=128;s>0;s>>=1){ if(tid<s) red[tid]+=red[tid+s]; __syncthreads(); }
        float sumi = red[0]; __syncthreads();
        red[tid]=eo; __syncthreads();
        for (int s=128;s>0;s>>=1){ if(tid<s) red[tid]+=red[tid+s]; __syncthreads(); }
        float sumo = red[0]; __syncthreads();

        if (tid<NN_){ ain[tid]=ei/sumi; aout[tid]=eo/sumo; }
        __syncthreads();

        float hi = 0.f, ho = 0.f;
        if (tid < D_){
            for (int k=0;k<NN_;++k) hi += ain[k]*ent_v[((long)(ient[k])*3+v)*D_ + tid];
        } else if (tid >= 128 && tid < 128+D_){
            int d = tid-128;
            for (int k=0;k<NN_;++k) ho += aout[k]*ent_v[((long)(oent[k])*3+v)*D_ + d];
            hof[d]=ho;
        }
        __syncthreads();
        if (tid < D_){
            float a = hi, c = hof[tid];
            float ea = __expf(a), ec = __expf(c);
            dst[v*DM_ + tid] = tanhf((a*ea + c*ec)/(ea+ec));
        }
        __syncthreads();
    }
}

// ---------------------------------------------------------------------------
// Kernel 3: senc.  grid = 777 (768 query rows + 9 support rows), 512 thr.
__global__ __launch_bounds__(512) void senc_kernel(
    const float* __restrict__ qn, const float* __restrict__ sn,
    const float* __restrict__ seW1, const float* __restrict__ seb1,
    const float* __restrict__ seW2, const float* __restrict__ seb2,
    const float* __restrict__ ln_g, const float* __restrict__ ln_b,
    float* __restrict__ qg, float* __restrict__ sEnc)
{
    int b = blockIdx.x, tid = threadIdx.x;
    const float* x; float* out;
    if (b < 768){ int n=b&255, v=b>>8; x=qn + n*600 + v*DM_; out=qg + (v*256+n)*DM_; }
    else        { int s=b-768;         x=sn + (s/3)*600 + (s%3)*DM_; out=sEnc + s*DM_; }

    __shared__ float xs[DM_];
    __shared__ float t1[DI_];
    __shared__ float red[512];

    if (tid < DM_) xs[tid] = x[tid];
    __syncthreads();
    if (tid < DI_){
        float a = seb1[tid];
        for (int i=0;i<DM_;++i) a += xs[i]*seW1[i*DI_ + tid];
        t1[tid] = fmaxf(a, 0.f);
    }
    __syncthreads();
    float h = 0.f;
    if (tid < DM_){
        h = seb2[tid] + xs[tid];
        for (int i=0;i<DI_;++i) h += t1[i]*seW2[i*DM_ + tid];
    }
    red[tid] = (tid<DM_)? h : 0.f; __syncthreads();
    for (int s=256;s>0;s>>=1){ if(tid<s) red[tid]+=red[tid+s]; __syncthreads(); }
    float mu = red[0]/DM_; __syncthreads();
    float dv = (tid<DM_)? (h-mu)*(h-mu) : 0.f;
    red[tid]=dv; __syncthreads();
    for (int s=256;s>0;s>>=1){ if(tid<s) red[tid]+=red[tid+s]; __syncthreads(); }
    float var = red[0]/DM_; __syncthreads();
    if (tid < DM_) out[tid] = ln_g[tid]*(h-mu)/sqrtf(var+1e-5f) + ln_b[tid];
}

// ---------------------------------------------------------------------------
__global__ void sgmean_kernel(const float* __restrict__ sEnc, float* __restrict__ sg){
    int i = blockIdx.x*blockDim.x + threadIdx.x;
    if (i < 600) sg[i] = (sEnc[i] + sEnc[600+i] + sEnc[1200+i]) * (1.f/3.f);
}

// ---------------------------------------------------------------------------
// Kernel 5: qW = qg @ Wih + bih + bhh   (768 x 1600).  grid = 96, 256 thr, 8 rows/blk
__global__ __launch_bounds__(256) void qw_kernel(
    const float* __restrict__ qg, const float* __restrict__ Wih,
    const float* __restrict__ bih, const float* __restrict__ bhh,
    float* __restrict__ qW)
{
    int b = blockIdx.x, tid = threadIdx.x;
    int row0 = b*8;
    __shared__ float xs[8][DM_];
    for (int idx=tid; idx<8*DM_; idx+=256) (&xs[0][0])[idx] = qg[row0*DM_ + idx];
    __syncthreads();
    for (int col=tid; col<G4_; col+=256){
        float bbv = bih[col] + bhh[col];
        float acc[8];
        #pragma unroll
        for (int r=0;r<8;++r) acc[r]=bbv;
        for (int i=0;i<DM_;++i){
            float w = Wih[i*G4_ + col];
            #pragma unroll
            for (int r=0;r<8;++r) acc[r] += xs[r][i]*w;
        }
        #pragma unroll
        for (int r=0;r<8;++r) qW[(row0+r)*G4_ + col] = acc[r];
    }
}

// ---------------------------------------------------------------------------
// Kernel 6: fused 4-step LSTM scan + support attention + final view score.
// grid = 192 blocks x 512 thr, 4 rows per block. All rows of a block share view v.
#define QROWS_ 4
__global__ __launch_bounds__(512) void qenc_kernel(
    const float* __restrict__ qg, const float* __restrict__ qW,
    const float* __restrict__ Whh, const float* __restrict__ sg,
    float* __restrict__ sAll)
{
    int b = blockIdx.x, tid = threadIdx.x;
    int row0 = b*QROWS_;
    int v = row0 >> 8;

    __shared__ float hr[QROWS_][DI_];
    __shared__ float cs[QROWS_][DI_];
    __shared__ float qs[QROWS_][DM_];
    __shared__ float sup[3][DM_];
    __shared__ float lg[QROWS_][3];

    for (int idx=tid; idx<QROWS_*DI_; idx+=512){ (&hr[0][0])[idx]=0.f; (&cs[0][0])[idx]=0.f; }
    for (int idx=tid; idx<QROWS_*DM_; idx+=512) (&qs[0][0])[idx] = qg[row0*DM_ + idx];
    for (int idx=tid; idx<3*DM_;      idx+=512) (&sup[0][0])[idx] = sg[idx];
    __syncthreads();

    for (int step=0; step<NSTEPS_; ++step){
        int j = tid;
        float a0[QROWS_], a1[QROWS_], a2[QROWS_], a3[QROWS_];
        if (j < DI_){
            #pragma unroll
            for (int r=0;r<QROWS_;++r){
                const float* qwr = qW + (long)(row0+r)*G4_;
                a0[r]=qwr[j]; a1[r]=qwr[400+j]; a2[r]=qwr[800+j]; a3[r]=qwr[1200+j];
            }
            if (step > 0){
                for (int i=0;i<DI_;++i){
                    const float* wr = Whh + (long)i*G4_;
                    float w0=wr[j], w1=wr[400+j], w2=wr[800+j], w3=wr[1200+j];
                    #pragma unroll
                    for (int r=0;r<QROWS_;++r){
                        float hv = hr[r][i];
                        a0[r]+=hv*w0; a1[r]+=hv*w1; a2[r]+=hv*w2; a3[r]+=hv*w3;
                    }
                }
            }
        }
        __syncthreads();               // all reads of hr done
        if (j < DI_){
            #pragma unroll
            for (int r=0;r<QROWS_;++r){
                float c2 = sigf(a1[r])*cs[r][j] + sigf(a0[r])*tanhf(a2[r]);
                cs[r][j] = c2;
                float h2 = sigf(a3[r])*tanhf(c2);
                if (j < DM_) hr[r][j] = qs[r][j] + h2;
            }
        }
        __syncthreads();               // new h visible
        // logits[r][s] = dot(h_r, sup_s), 12 pairs x 16 lanes
        if (tid < 192){
            int p = tid>>4, l = tid&15, r = p/3, s = p%3;
            float part = 0.f;
            for (int d=l; d<DM_; d+=16) part += hr[r][d]*sup[s][d];
            for (int off=8; off; off>>=1) part += __shfl_down(part, off, 16);
            if (l==0) lg[r][s] = part;
        }
        __syncthreads();
        // r-vector -> hr[r][200:400]
        for (int idx=tid; idx<QROWS_*DM_; idx+=512){
            int r = idx/DM_, d = idx - r*DM_;
            float l0=lg[r][0], l1=lg[r][1], l2=lg[r][2];
            float m = fmaxf(l0, fmaxf(l1,l2));
            float e0=__expf(l0-m), e1=__expf(l1-m), e2=__expf(l2-m);
            float inv = 1.f/(e0+e1+e2);
            hr[r][DM_+d] = (e0*sup[0][d] + e1*sup[1][d] + e2*sup[2][d])*inv;
        }
        __syncthreads();
    }
    // final score vs sg[v]
    if (tid < QROWS_*16){
        int r = tid>>4, l = tid&15;
        float part = 0.f;
        for (int d=l; d<DM_; d+=16) part += hr[r][d]*sup[v][d];
        for (int off=8; off; off>>=1) part += __shfl_down(part, off, 16);
        if (l==0) sAll[row0+r] = part;
    }
}

// ---------------------------------------------------------------------------
__global__ void final_kernel(const float* __restrict__ sAll, float* __restrict__ out){
    int n = blockIdx.x*blockDim.x + threadIdx.x;
    if (n < 256) out[n] = fmaxf(sAll[n], fmaxf(sAll[256+n], sAll[512+n]));
}

// ---------------------------------------------------------------------------
extern "C" void kernel_launch(void* const* d_in, const int* in_sizes, int n_in,
                              void* d_out, int out_size, void* d_ws, size_t ws_size,
                              hipStream_t stream)
{
    const float* ent_emb=(const float*)d_in[0];
    const float* rel_emb=(const float*)d_in[1];
    const float* W1=(const float*)d_in[2];  const float* b1=(const float*)d_in[3];
    const float* W2=(const float*)d_in[4];  const float* b2=(const float*)d_in[5];
    const float* W3=(const float*)d_in[6];  const float* b3=(const float*)d_in[7];
    const float* attW1=(const float*)d_in[8];
    const float* attW2=(const float*)d_in[10];
    const float* seW1=(const float*)d_in[12]; const float* seb1=(const float*)d_in[13];
    const float* seW2=(const float*)d_in[14]; const float* seb2=(const float*)d_in[15];
    const float* ln_g=(const float*)d_in[16]; const float* ln_b=(const float*)d_in[17];
    const float* Wih=(const float*)d_in[18];  const float* bih=(const float*)d_in[19];
    const float* Whh=(const float*)d_in[20];  const float* bhh=(const float*)d_in[21];
    const int* qlc_out=(const int*)d_in[24];  const int* qlc_in=(const int*)d_in[25];
    const int* qrc_out=(const int*)d_in[27];  const int* qrc_in=(const int*)d_in[28];
    const int* slc_out=(const int*)d_in[30];  const int* slc_in=(const int*)d_in[31];
    const int* src_out=(const int*)d_in[33];  const int* src_in=(const int*)d_in[34];

    float* ws    = (float*)d_ws;
    float* ent_v = ws;                 // 5000*3*100 = 1,500,000
    float* rs_in = ent_v + 1500000;    // 15,000
    float* rs_out= rs_in + 15000;      // 15,000
    float* qn    = rs_out + 15000;     // 256*3*200 = 153,600
    float* sn    = qn + 153600;        // 1,800
    float* qg    = sn + 1800;          // 153,600
    float* sEnc  = qg + 153600;        // 1,800
    float* sg    = sEnc + 1800;        // 600
    float* qW    = sg + 600;           // 768*1600 = 1,228,800
    float* sAll  = qW + 1228800;       // 768

    views_kernel<<<1250, 128, 0, stream>>>(ent_emb, rel_emb, W1,b1,W2,b2,W3,b3,
                                           attW1, attW2, ent_v, rs_in, rs_out);
    neigh_kernel<<<518, 256, 0, stream>>>(qlc_out,qlc_in,qrc_out,qrc_in,
                                          slc_out,slc_in,src_out,src_in,
                                          ent_v, rs_in, rs_out, qn, sn);
    senc_kernel<<<777, 512, 0, stream>>>(qn, sn, seW1,seb1,seW2,seb2, ln_g,ln_b, qg, sEnc);
    sgmean_kernel<<<1, 600, 0, stream>>>(sEnc, sg);
    qw_kernel<<<96, 256, 0, stream>>>(qg, Wih, bih, bhh, qW);
    qenc_kernel<<<192, 512, 0, stream>>>(qg, qW, Whh, sg, sAll);
    final_kernel<<<1, 256, 0, stream>>>(sAll, (float*)d_out);
}

// Round 2
// 349.073 us; speedup vs baseline: 1.0637x; 1.0637x over previous
//
#include <hip/hip_runtime.h>
#include <math.h>

#define D_    100
#define DM_   200
#define DI_   400
#define G4_   1600
#define NN_   200

__device__ __forceinline__ float sigf(float x){ return 1.0f/(1.0f+__expf(-x)); }

// ---------------------------------------------------------------------------
// Kernel 1: views.  grid = 1250 blocks (625 rel-groups + 625 ent-groups), 128 thr
#define VROWS 8
__global__ __launch_bounds__(128) void views_kernel(
    const float* __restrict__ ent_emb, const float* __restrict__ rel_emb,
    const float* __restrict__ W1, const float* __restrict__ b1,
    const float* __restrict__ W2, const float* __restrict__ b2,
    const float* __restrict__ W3, const float* __restrict__ b3,
    const float* __restrict__ attW1, const float* __restrict__ attW2,
    float* __restrict__ ent_v, float* __restrict__ rs_in, float* __restrict__ rs_out)
{
    int bid = blockIdx.x, tid = threadIdx.x;
    bool isRel = bid < 625;
    int row0 = (isRel ? bid : bid - 625) * VROWS;
    const float* src = isRel ? rel_emb : ent_emb;

    __shared__ float e[VROWS][D_];
    __shared__ float ys[VROWS][D_];
    __shared__ float invn[VROWS];

    for (int idx = tid; idx < VROWS*D_; idx += 128) (&e[0][0])[idx] = src[row0*D_ + idx];
    __syncthreads();

    const float* W[3]  = {W1, W2, W3};
    const float* bb[3] = {b1, b2, b3};

    #pragma unroll
    for (int v = 0; v < 3; ++v){
        float y[VROWS];
        if (tid < D_){
            float bv = bb[v][tid];
            #pragma unroll
            for (int r = 0; r < VROWS; ++r) y[r] = bv;
            const float* Wv = W[v];
            for (int i = 0; i < D_; ++i){
                float w = Wv[i*D_ + tid];
                #pragma unroll
                for (int r = 0; r < VROWS; ++r) y[r] += e[r][i] * w;
            }
            #pragma unroll
            for (int r = 0; r < VROWS; ++r) ys[r][tid] = y[r];
        }
        __syncthreads();
        if (tid < VROWS){
            float s = 0.f;
            for (int j = 0; j < D_; ++j){ float t = ys[tid][j]; s += t*t; }
            invn[tid] = 1.f / fmaxf(sqrtf(s), 1e-12f);
        }
        __syncthreads();
        if (isRel){
            if (tid < VROWS){
                float inv = invn[tid], s1 = 0.f, s2 = 0.f;
                for (int j = 0; j < D_; ++j){
                    float t = ys[tid][j] * inv;
                    s1 += t * attW1[j];
                    s2 += t * attW2[j];
                }
                rs_in [(row0+tid)*3 + v] = s1;
                rs_out[(row0+tid)*3 + v] = s2;
            }
        } else {
            if (tid < D_){
                #pragma unroll
                for (int r = 0; r < VROWS; ++r)
                    ent_v[(((long)(row0+r))*3 + v)*D_ + tid] = y[r] * invn[r];
            }
        }
        __syncthreads();
    }
}

// ---------------------------------------------------------------------------
// Kernel 2: neigh.  grid = 518, 256 thr.
__global__ __launch_bounds__(256) void neigh_kernel(
    const int* __restrict__ qlc_out, const int* __restrict__ qlc_in,
    const int* __restrict__ qrc_out, const int* __restrict__ qrc_in,
    const int* __restrict__ slc_out, const int* __restrict__ slc_in,
    const int* __restrict__ src_out, const int* __restrict__ src_in,
    const float* __restrict__ ent_v, const float* __restrict__ rs_in,
    const float* __restrict__ rs_out,
    float* __restrict__ qn, float* __restrict__ sn)
{
    int b = blockIdx.x, tid = threadIdx.x;
    const int *cin, *cout; float* dst;
    if      (b < 256){ int n=b;     cout=qlc_out+n*NN_*2; cin=qlc_in+n*NN_*2; dst=qn+n*600;      }
    else if (b < 512){ int n=b-256; cout=qrc_out+n*NN_*2; cin=qrc_in+n*NN_*2; dst=qn+n*600+100;  }
    else if (b < 515){ int n=b-512; cout=slc_out+n*NN_*2; cin=slc_in+n*NN_*2; dst=sn+n*600;      }
    else             { int n=b-515; cout=src_out+n*NN_*2; cin=src_in+n*NN_*2; dst=sn+n*600+100;  }

    __shared__ int irel[NN_], ient[NN_], orel[NN_], oent[NN_];
    __shared__ float ain[NN_], aout[NN_];
    __shared__ float red[256];
    __shared__ float hof[D_];

    if (tid < NN_){
        irel[tid]=cin [tid*2]; ient[tid]=cin [tid*2+1];
        orel[tid]=cout[tid*2]; oent[tid]=cout[tid*2+1];
    }
    __syncthreads();

    for (int v = 0; v < 3; ++v){
        float si = (tid<NN_) ? rs_in [irel[tid]*3+v] : -1e30f;
        float so = (tid<NN_) ? rs_out[orel[tid]*3+v] : -1e30f;

        red[tid]=si; __syncthreads();
        for (int s=128;s>0;s>>=1){ if(tid<s) red[tid]=fmaxf(red[tid],red[tid+s]); __syncthreads(); }
        float mi = red[0]; __syncthreads();
        red[tid]=so; __syncthreads();
        for (int s=128;s>0;s>>=1){ if(tid<s) red[tid]=fmaxf(red[tid],red[tid+s]); __syncthreads(); }
        float mo = red[0]; __syncthreads();

        float ei = (tid<NN_) ? __expf(si-mi) : 0.f;
        float eo = (tid<NN_) ? __expf(so-mo) : 0.f;
        red[tid]=ei; __syncthreads();
        for (int s=128;s>0;s>>=1){ if(tid<s) red[tid]+=red[tid+s]; __syncthreads(); }
        float sumi = red[0]; __syncthreads();
        red[tid]=eo; __syncthreads();
        for (int s=128;s>0;s>>=1){ if(tid<s) red[tid]+=red[tid+s]; __syncthreads(); }
        float sumo = red[0]; __syncthreads();

        if (tid<NN_){ ain[tid]=ei/sumi; aout[tid]=eo/sumo; }
        __syncthreads();

        float hi = 0.f, ho = 0.f;
        if (tid < D_){
            for (int k=0;k<NN_;++k) hi += ain[k]*ent_v[((long)(ient[k])*3+v)*D_ + tid];
        } else if (tid >= 128 && tid < 128+D_){
            int d = tid-128;
            for (int k=0;k<NN_;++k) ho += aout[k]*ent_v[((long)(oent[k])*3+v)*D_ + d];
            hof[d]=ho;
        }
        __syncthreads();
        if (tid < D_){
            float a = hi, c = hof[tid];
            float ea = __expf(a), ec = __expf(c);
            dst[v*DM_ + tid] = tanhf((a*ea + c*ec)/(ea+ec));
        }
        __syncthreads();
    }
}

// ---------------------------------------------------------------------------
// Kernel 3: senc.  grid = 777, 512 thr.
__global__ __launch_bounds__(512) void senc_kernel(
    const float* __restrict__ qn, const float* __restrict__ sn,
    const float* __restrict__ seW1, const float* __restrict__ seb1,
    const float* __restrict__ seW2, const float* __restrict__ seb2,
    const float* __restrict__ ln_g, const float* __restrict__ ln_b,
    float* __restrict__ qg, float* __restrict__ sEnc)
{
    int b = blockIdx.x, tid = threadIdx.x;
    const float* x; float* out;
    if (b < 768){ int n=b&255, v=b>>8; x=qn + n*600 + v*DM_; out=qg + (v*256+n)*DM_; }
    else        { int s=b-768;         x=sn + (s/3)*600 + (s%3)*DM_; out=sEnc + s*DM_; }

    __shared__ float xs[DM_];
    __shared__ float t1[DI_];
    __shared__ float red[512];

    if (tid < DM_) xs[tid] = x[tid];
    __syncthreads();
    if (tid < DI_){
        float a = seb1[tid];
        for (int i=0;i<DM_;++i) a += xs[i]*seW1[i*DI_ + tid];
        t1[tid] = fmaxf(a, 0.f);
    }
    __syncthreads();
    float h = 0.f;
    if (tid < DM_){
        h = seb2[tid] + xs[tid];
        for (int i=0;i<DI_;++i) h += t1[i]*seW2[i*DM_ + tid];
    }
    red[tid] = (tid<DM_)? h : 0.f; __syncthreads();
    for (int s=256;s>0;s>>=1){ if(tid<s) red[tid]+=red[tid+s]; __syncthreads(); }
    float mu = red[0]/DM_; __syncthreads();
    float dv = (tid<DM_)? (h-mu)*(h-mu) : 0.f;
    red[tid]=dv; __syncthreads();
    for (int s=256;s>0;s>>=1){ if(tid<s) red[tid]+=red[tid+s]; __syncthreads(); }
    float var = red[0]/DM_; __syncthreads();
    if (tid < DM_) out[tid] = ln_g[tid]*(h-mu)/sqrtf(var+1e-5f) + ln_b[tid];
}

// ---------------------------------------------------------------------------
__global__ void sgmean_kernel(const float* __restrict__ sEnc, float* __restrict__ sg){
    int i = blockIdx.x*blockDim.x + threadIdx.x;
    if (i < 600) sg[i] = (sEnc[i] + sEnc[600+i] + sEnc[1200+i]) * (1.f/3.f);
}

// ---------------------------------------------------------------------------
// sW[s][col] = sum_i sup[s][i] * Whh[200+i][col]   (3 x 1600)
__global__ void sw_kernel(const float* __restrict__ sg, const float* __restrict__ Whh,
                          float* __restrict__ sW){
    int idx = blockIdx.x*64 + threadIdx.x;
    if (idx >= 4800) return;
    int s = idx/1600, col = idx - s*1600;
    float acc = 0.f;
    for (int i=0;i<DM_;++i) acc += sg[s*DM_+i]*Whh[(long)(DM_+i)*G4_ + col];
    sW[idx] = acc;
}

// ---------------------------------------------------------------------------
// Tiled fp32 GEMM: C[768x1600] = A[768x200] @ B[200x1600] + epilogue.
// mode 0: += bih+bhh.  mode 1: += qW0 + alpha·sW.
// tile 32x64, 128 thr (8x16, 4x4 per thread), grid 24*25=600.
__global__ __launch_bounds__(128) void gemm_kernel(
    const float* __restrict__ A, const float* __restrict__ B,
    const float* __restrict__ qW0, const float* __restrict__ sW,
    const float* __restrict__ alpha,
    const float* __restrict__ bih, const float* __restrict__ bhh,
    float* __restrict__ C, int mode)
{
    int bx = blockIdx.x % 25, by = blockIdx.x / 25;
    int row0 = by*32, col0 = bx*64;
    int tid = threadIdx.x;

    __shared__ float As[200][32];   // As[k][r]
    __shared__ float Bs[200][64];   // Bs[k][c]
    __shared__ float alf[32][3];

    // stage A: lane idx -> r = idx&31, kc = idx>>5 (conflict-free LDS writes)
    for (int idx = tid; idx < 32*50; idx += 128){
        int r = idx & 31, kc = idx >> 5;
        float4 a4 = *(const float4*)(A + (long)(row0+r)*DM_ + kc*4);
        As[kc*4+0][r]=a4.x; As[kc*4+1][r]=a4.y; As[kc*4+2][r]=a4.z; As[kc*4+3][r]=a4.w;
    }
    // stage B: 200 rows x 16 float4, linear writes
    for (int idx = tid; idx < 200*16; idx += 128){
        int k = idx >> 4, c4 = idx & 15;
        *(float4*)(&Bs[k][c4*4]) = *(const float4*)(B + (long)k*G4_ + col0 + c4*4);
    }
    if (mode == 1){
        for (int idx = tid; idx < 96; idx += 128)
            alf[idx/3][idx%3] = alpha[(row0 + idx/3)*3 + idx%3];
    }
    __syncthreads();

    int tx = tid & 15, ty = tid >> 4;
    float acc[4][4] = {};
    #pragma unroll 2
    for (int k = 0; k < 200; ++k){
        float4 a = *(const float4*)(&As[k][ty*4]);
        float4 b = *(const float4*)(&Bs[k][tx*4]);
        acc[0][0]+=a.x*b.x; acc[0][1]+=a.x*b.y; acc[0][2]+=a.x*b.z; acc[0][3]+=a.x*b.w;
        acc[1][0]+=a.y*b.x; acc[1][1]+=a.y*b.y; acc[1][2]+=a.y*b.z; acc[1][3]+=a.y*b.w;
        acc[2][0]+=a.z*b.x; acc[2][1]+=a.z*b.y; acc[2][2]+=a.z*b.z; acc[2][3]+=a.z*b.w;
        acc[3][0]+=a.w*b.x; acc[3][1]+=a.w*b.y; acc[3][2]+=a.w*b.z; acc[3][3]+=a.w*b.w;
    }

    int cc0 = col0 + tx*4;
    if (mode == 0){
        float4 u = *(const float4*)(bih + cc0);
        float4 w = *(const float4*)(bhh + cc0);
        float4 add = make_float4(u.x+w.x, u.y+w.y, u.z+w.z, u.w+w.w);
        #pragma unroll
        for (int r = 0; r < 4; ++r){
            int row = row0 + ty*4 + r;
            float4 o = make_float4(acc[r][0]+add.x, acc[r][1]+add.y, acc[r][2]+add.z, acc[r][3]+add.w);
            *(float4*)(C + (long)row*G4_ + cc0) = o;
        }
    } else {
        float4 s0 = *(const float4*)(sW + 0*G4_ + cc0);
        float4 s1 = *(const float4*)(sW + 1*G4_ + cc0);
        float4 s2 = *(const float4*)(sW + 2*G4_ + cc0);
        #pragma unroll
        for (int r = 0; r < 4; ++r){
            int row = row0 + ty*4 + r;
            float a0 = alf[ty*4+r][0], a1 = alf[ty*4+r][1], a2 = alf[ty*4+r][2];
            float4 q = *(const float4*)(qW0 + (long)row*G4_ + cc0);
            float4 o;
            o.x = acc[r][0] + q.x + a0*s0.x + a1*s1.x + a2*s2.x;
            o.y = acc[r][1] + q.y + a0*s0.y + a1*s1.y + a2*s2.y;
            o.z = acc[r][2] + q.z + a0*s0.z + a1*s1.z + a2*s2.z;
            o.w = acc[r][3] + q.w + a0*s0.w + a1*s1.w + a2*s2.w;
            *(float4*)(C + (long)row*G4_ + cc0) = o;
        }
    }
}

// ---------------------------------------------------------------------------
// LSTM cell + support attention. grid 192 x 256 thr, 4 rows/block.
// first: c_old = 0.  last: write score sAll instead of alpha.
__global__ __launch_bounds__(256) void cell_kernel(
    const float* __restrict__ G, const float* __restrict__ qg,
    const float* __restrict__ sg, float* __restrict__ c,
    float* __restrict__ h, float* __restrict__ alpha, float* __restrict__ sAll,
    int first, int last)
{
    int b = blockIdx.x, tid = threadIdx.x;
    int row0 = b*4;
    __shared__ float hbuf[4][DM_];
    __shared__ float sup[600];
    __shared__ float lg[4][3];

    for (int i = tid; i < 600; i += 256) sup[i] = sg[i];

    for (int idx = tid; idx < 4*DI_; idx += 256){
        int r = idx / DI_, j = idx - r*DI_;
        int row = row0 + r;
        const float* g = G + (long)row*G4_;
        float gi = g[j], gf = g[DI_+j], gg = g[2*DI_+j];
        float cold = first ? 0.f : c[(long)row*DI_ + j];
        float c2 = sigf(gf)*cold + sigf(gi)*tanhf(gg);
        c[(long)row*DI_ + j] = c2;
        if (j < DM_){
            float go = g[3*DI_+j];
            float hv = qg[(long)row*DM_ + j] + sigf(go)*tanhf(c2);
            hbuf[r][j] = hv;
            h[(long)row*DM_ + j] = hv;
        }
    }
    __syncthreads();

    if (!last){
        if (tid < 192){
            int p = tid >> 4, l = tid & 15, r = p/3, s = p - r*3;
            float part = 0.f;
            for (int d = l; d < DM_; d += 16) part += hbuf[r][d]*sup[s*DM_+d];
            for (int o = 8; o; o >>= 1) part += __shfl_down(part, o, 16);
            if (!l) lg[r][s] = part;
        }
        __syncthreads();
        if (tid < 4){
            float l0 = lg[tid][0], l1 = lg[tid][1], l2 = lg[tid][2];
            float m = fmaxf(l0, fmaxf(l1, l2));
            float e0 = __expf(l0-m), e1 = __expf(l1-m), e2 = __expf(l2-m);
            float inv = 1.f/(e0+e1+e2);
            alpha[(row0+tid)*3+0] = e0*inv;
            alpha[(row0+tid)*3+1] = e1*inv;
            alpha[(row0+tid)*3+2] = e2*inv;
        }
    } else {
        int v = row0 >> 8;
        if (tid < 64){
            int r = tid >> 4, l = tid & 15;
            float part = 0.f;
            for (int d = l; d < DM_; d += 16) part += hbuf[r][d]*sup[v*DM_+d];
            for (int o = 8; o; o >>= 1) part += __shfl_down(part, o, 16);
            if (!l) sAll[row0+r] = part;
        }
    }
}

// ---------------------------------------------------------------------------
__global__ void final_kernel(const float* __restrict__ sAll, float* __restrict__ out){
    int n = blockIdx.x*blockDim.x + threadIdx.x;
    if (n < 256) out[n] = fmaxf(sAll[n], fmaxf(sAll[256+n], sAll[512+n]));
}

// ---------------------------------------------------------------------------
extern "C" void kernel_launch(void* const* d_in, const int* in_sizes, int n_in,
                              void* d_out, int out_size, void* d_ws, size_t ws_size,
                              hipStream_t stream)
{
    const float* ent_emb=(const float*)d_in[0];
    const float* rel_emb=(const float*)d_in[1];
    const float* W1=(const float*)d_in[2];  const float* b1=(const float*)d_in[3];
    const float* W2=(const float*)d_in[4];  const float* b2=(const float*)d_in[5];
    const float* W3=(const float*)d_in[6];  const float* b3=(const float*)d_in[7];
    const float* attW1=(const float*)d_in[8];
    const float* attW2=(const float*)d_in[10];
    const float* seW1=(const float*)d_in[12]; const float* seb1=(const float*)d_in[13];
    const float* seW2=(const float*)d_in[14]; const float* seb2=(const float*)d_in[15];
    const float* ln_g=(const float*)d_in[16]; const float* ln_b=(const float*)d_in[17];
    const float* Wih=(const float*)d_in[18];  const float* bih=(const float*)d_in[19];
    const float* Whh=(const float*)d_in[20];  const float* bhh=(const float*)d_in[21];
    const int* qlc_out=(const int*)d_in[24];  const int* qlc_in=(const int*)d_in[25];
    const int* qrc_out=(const int*)d_in[27];  const int* qrc_in=(const int*)d_in[28];
    const int* slc_out=(const int*)d_in[30];  const int* slc_in=(const int*)d_in[31];
    const int* src_out=(const int*)d_in[33];  const int* src_in=(const int*)d_in[34];

    float* ws    = (float*)d_ws;
    float* ent_v = ws;                 // 1,500,000 (dead after neigh -> reused as gates)
    float* rs_in = ws + 1500000;       // 15,000
    float* rs_out= ws + 1515000;       // 15,000
    float* qn    = ws + 1530000;       // 153,600 (dead after senc -> reused as h)
    float* sn    = ws + 1683600;       // 1,800
    float* qg    = ws + 1685400;       // 153,600
    float* sEnc  = ws + 1839000;       // 1,800
    float* sg    = ws + 1840800;       // 600
    float* qW0   = ws + 1841400;       // 1,228,800
    float* cst   = ws + 3070200;       // 307,200
    float* alpha = ws + 3377400;       // 2,304
    float* sW    = ws + 3379704;       // 4,800
    float* sAll  = ws + 3384504;       // 768
    float* gates = ent_v;              // 1,228,800 <= 1,500,000
    float* h     = qn;                 // 153,600

    views_kernel<<<1250, 128, 0, stream>>>(ent_emb, rel_emb, W1,b1,W2,b2,W3,b3,
                                           attW1, attW2, ent_v, rs_in, rs_out);
    neigh_kernel<<<518, 256, 0, stream>>>(qlc_out,qlc_in,qrc_out,qrc_in,
                                          slc_out,slc_in,src_out,src_in,
                                          ent_v, rs_in, rs_out, qn, sn);
    senc_kernel<<<777, 512, 0, stream>>>(qn, sn, seW1,seb1,seW2,seb2, ln_g,ln_b, qg, sEnc);
    sgmean_kernel<<<1, 600, 0, stream>>>(sEnc, sg);
    sw_kernel<<<75, 64, 0, stream>>>(sg, Whh, sW);

    // qW0 = qg @ Wih + bih + bhh
    gemm_kernel<<<600, 128, 0, stream>>>(qg, Wih, nullptr, nullptr, nullptr,
                                         bih, bhh, qW0, 0);
    // step 0: gates = qW0
    cell_kernel<<<192, 256, 0, stream>>>(qW0, qg, sg, cst, h, alpha, sAll, 1, 0);
    // steps 1..3
    for (int s = 1; s < 4; ++s){
        gemm_kernel<<<600, 128, 0, stream>>>(h, Whh, qW0, sW, alpha,
                                             nullptr, nullptr, gates, 1);
        cell_kernel<<<192, 256, 0, stream>>>(gates, qg, sg, cst, h, alpha, sAll,
                                             0, (s==3) ? 1 : 0);
    }
    final_kernel<<<1, 256, 0, stream>>>(sAll, (float*)d_out);
}

// Round 3
// 245.624 us; speedup vs baseline: 1.5117x; 1.4212x over previous
//
#include <hip/hip_runtime.h>
#include <math.h>

#define D_    100
#define DM_   200
#define DI_   400
#define G4_   1600
#define NN_   200

__device__ __forceinline__ float sigf(float x){ return 1.0f/(1.0f+__expf(-x)); }
__device__ __forceinline__ unsigned short f2bf(float f){
    unsigned int b = __float_as_uint(f);
    b = (b + 0x7fffu + ((b>>16)&1u)) >> 16;
    return (unsigned short)b;
}
__device__ __forceinline__ float bf_lo(unsigned int w){ return __uint_as_float(w<<16); }
__device__ __forceinline__ float bf_hi(unsigned int w){ return __uint_as_float(w & 0xffff0000u); }

// ---------------------------------------------------------------------------
// Kernel 1: views.  grid = 1250 (625 rel-groups + 625 ent-groups), 128 thr.
// rel rows -> scalar attention scores; ent rows (0..4999) -> bf16 views.
#define VROWS 8
__global__ __launch_bounds__(128) void views_kernel(
    const float* __restrict__ ent_emb, const float* __restrict__ rel_emb,
    const float* __restrict__ W1, const float* __restrict__ b1,
    const float* __restrict__ W2, const float* __restrict__ b2,
    const float* __restrict__ W3, const float* __restrict__ b3,
    const float* __restrict__ attW1, const float* __restrict__ attW2,
    unsigned short* __restrict__ ent_bf, float* __restrict__ rs_in, float* __restrict__ rs_out)
{
    int bid = blockIdx.x, tid = threadIdx.x;
    bool isRel = bid < 625;
    int row0 = (isRel ? bid : bid - 625) * VROWS;
    const float* src = isRel ? rel_emb : ent_emb;

    __shared__ float e[VROWS][D_];
    __shared__ float ys[VROWS][D_];
    __shared__ float invn[VROWS];

    for (int idx = tid; idx < VROWS*D_; idx += 128) (&e[0][0])[idx] = src[row0*D_ + idx];
    __syncthreads();

    const float* W[3]  = {W1, W2, W3};
    const float* bb[3] = {b1, b2, b3};

    #pragma unroll
    for (int v = 0; v < 3; ++v){
        float y[VROWS];
        if (tid < D_){
            float bv = bb[v][tid];
            #pragma unroll
            for (int r = 0; r < VROWS; ++r) y[r] = bv;
            const float* Wv = W[v];
            for (int i = 0; i < D_; ++i){
                float w = Wv[i*D_ + tid];
                #pragma unroll
                for (int r = 0; r < VROWS; ++r) y[r] += e[r][i] * w;
            }
            #pragma unroll
            for (int r = 0; r < VROWS; ++r) ys[r][tid] = y[r];
        }
        __syncthreads();
        if (tid < VROWS){
            float s = 0.f;
            for (int j = 0; j < D_; ++j){ float t = ys[tid][j]; s += t*t; }
            invn[tid] = 1.f / fmaxf(sqrtf(s), 1e-12f);
        }
        __syncthreads();
        if (isRel){
            if (tid < VROWS){
                float inv = invn[tid], s1 = 0.f, s2 = 0.f;
                for (int j = 0; j < D_; ++j){
                    float t = ys[tid][j] * inv;
                    s1 += t * attW1[j];
                    s2 += t * attW2[j];
                }
                rs_in [(row0+tid)*3 + v] = s1;
                rs_out[(row0+tid)*3 + v] = s2;
            }
        } else {
            if (tid < D_){
                #pragma unroll
                for (int r = 0; r < VROWS; ++r)
                    ent_bf[(((long)(row0+r))*3 + v)*D_ + tid] = f2bf(y[r] * invn[r]);
            }
        }
        __syncthreads();
    }
}

// ---------------------------------------------------------------------------
// Kernel 2: neigh.  grid = (518, 3), 512 thr. One block per (unit, view).
__global__ __launch_bounds__(512) void neigh_kernel(
    const int* __restrict__ qlc_out, const int* __restrict__ qlc_in,
    const int* __restrict__ qrc_out, const int* __restrict__ qrc_in,
    const int* __restrict__ slc_out, const int* __restrict__ slc_in,
    const int* __restrict__ src_out, const int* __restrict__ src_in,
    const unsigned short* __restrict__ ent_bf, const float* __restrict__ rs_in,
    const float* __restrict__ rs_out,
    float* __restrict__ qn, float* __restrict__ sn)
{
    int u = blockIdx.x, v = blockIdx.y, tid = threadIdx.x;
    const int *cin, *cout; float* dst;
    if      (u < 256){ int n=u;     cout=qlc_out+n*NN_*2; cin=qlc_in+n*NN_*2; dst=qn+n*600;      }
    else if (u < 512){ int n=u-256; cout=qrc_out+n*NN_*2; cin=qrc_in+n*NN_*2; dst=qn+n*600+100;  }
    else if (u < 515){ int n=u-512; cout=slc_out+n*NN_*2; cin=slc_in+n*NN_*2; dst=sn+n*600;      }
    else             { int n=u-515; cout=src_out+n*NN_*2; cin=src_in+n*NN_*2; dst=sn+n*600+100;  }

    __shared__ int   ioff[NN_], ooff[NN_];
    __shared__ float ain[NN_], aout[NN_];
    __shared__ float sv[2][NN_];
    __shared__ float red[512];
    __shared__ float pin[4][D_], pout[4][D_];

    if (tid < NN_){
        int rrel = cin[tid*2], rent = cin[tid*2+1];
        ioff[tid] = (rent*3+v)*D_;
        sv[0][tid] = rs_in[rrel*3+v];
    } else if (tid >= 256 && tid < 256+NN_){
        int k = tid - 256;
        int rrel = cout[k*2], rent = cout[k*2+1];
        ooff[k] = (rent*3+v)*D_;
        sv[1][k] = rs_out[rrel*3+v];
    }
    __syncthreads();

    // dual softmax: half 0 = in, half 1 = out
    int half = tid >> 8, l = tid & 255, base = half << 8;
    float x = (l < NN_) ? sv[half][l] : -1e30f;
    red[tid] = x; __syncthreads();
    for (int s = 128; s > 0; s >>= 1){
        if (l < s) red[base+l] = fmaxf(red[base+l], red[base+l+s]);
        __syncthreads();
    }
    float m = red[base]; __syncthreads();
    float e = (l < NN_) ? __expf(x - m) : 0.f;
    red[tid] = e; __syncthreads();
    for (int s = 128; s > 0; s >>= 1){
        if (l < s) red[base+l] += red[base+l+s];
        __syncthreads();
    }
    float S = red[base];
    if (l < NN_){ if (half) aout[l] = e/S; else ain[l] = e/S; }
    __syncthreads();

    // gather: 8 wave-groups; g<4: in (k-quarter g), g>=4: out (k-quarter g-4)
    int g = tid >> 6, ln = tid & 63;
    if (ln < 50){
        int d0 = ln*2;
        bool isOut = g >= 4;
        int k0 = (g & 3) * 50;
        const int*   offA = isOut ? ooff : ioff;
        const float* aA   = isOut ? aout : ain;
        float acc0 = 0.f, acc1 = 0.f;
        #pragma unroll 5
        for (int kk = 0; kk < 50; ++kk){
            int k = k0 + kk;
            unsigned int w = *(const unsigned int*)(ent_bf + offA[k] + d0);
            float a = aA[k];
            acc0 += a * bf_lo(w);
            acc1 += a * bf_hi(w);
        }
        float2* p = isOut ? (float2*)&pout[g&3][d0] : (float2*)&pin[g&3][d0];
        *p = make_float2(acc0, acc1);
    }
    __syncthreads();

    if (tid < D_){
        float hi = pin[0][tid]+pin[1][tid]+pin[2][tid]+pin[3][tid];
        float ho = pout[0][tid]+pout[1][tid]+pout[2][tid]+pout[3][tid];
        float ea = __expf(hi), ec = __expf(ho);
        dst[v*DM_ + tid] = tanhf((hi*ea + ho*ec)/(ea+ec));
    }
}

// ---------------------------------------------------------------------------
// Kernel 3: senc, 4 rows/block.  grid = 195, 512 thr. 777 total rows.
__global__ __launch_bounds__(512) void senc_kernel(
    const float* __restrict__ qn, const float* __restrict__ sn,
    const float* __restrict__ seW1, const float* __restrict__ seb1,
    const float* __restrict__ seW2, const float* __restrict__ seb2,
    const float* __restrict__ ln_g, const float* __restrict__ ln_b,
    float* __restrict__ qg, float* __restrict__ sEnc)
{
    int b = blockIdx.x, tid = threadIdx.x;
    int r0 = b*4;

    __shared__ float xs[4][DM_];
    __shared__ float t1s[4][DI_];
    __shared__ float hv[4][DM_];
    __shared__ float red[512];
    __shared__ float m4[4], v4[4];

    // load inputs
    for (int idx = tid; idx < 4*DM_; idx += 512){
        int rr = idx / DM_, j = idx - rr*DM_;
        int r = r0 + rr;
        if (r < 777){
            const float* xp;
            if (r < 768){ int n = r & 255, v = r >> 8; xp = qn + n*600 + v*DM_; }
            else        { int s = r - 768;             xp = sn + (s/3)*600 + (s%3)*DM_; }
            xs[rr][j] = xp[j];
        }
    }
    __syncthreads();

    if (tid < DI_){
        float a0, a1, a2, a3;
        float bv = seb1[tid];
        a0 = a1 = a2 = a3 = bv;
        for (int i = 0; i < DM_; ++i){
            float w = seW1[i*DI_ + tid];
            a0 += xs[0][i]*w; a1 += xs[1][i]*w; a2 += xs[2][i]*w; a3 += xs[3][i]*w;
        }
        t1s[0][tid] = fmaxf(a0,0.f); t1s[1][tid] = fmaxf(a1,0.f);
        t1s[2][tid] = fmaxf(a2,0.f); t1s[3][tid] = fmaxf(a3,0.f);
    }
    __syncthreads();

    if (tid < DM_){
        float bv = seb2[tid];
        float h0 = bv + xs[0][tid], h1 = bv + xs[1][tid], h2 = bv + xs[2][tid], h3 = bv + xs[3][tid];
        for (int i = 0; i < DI_; ++i){
            float w = seW2[i*DM_ + tid];
            h0 += t1s[0][i]*w; h1 += t1s[1][i]*w; h2 += t1s[2][i]*w; h3 += t1s[3][i]*w;
        }
        hv[0][tid]=h0; hv[1][tid]=h1; hv[2][tid]=h2; hv[3][tid]=h3;
    }
    __syncthreads();

    // per-row mean/var: 4 groups of 128 threads
    int g = tid >> 7, l = tid & 127;
    float s1 = hv[g][l] + ((l < DM_-128) ? hv[g][l+128] : 0.f);
    red[tid] = s1; __syncthreads();
    for (int s = 64; s > 0; s >>= 1){ if (l < s) red[(g<<7)+l] += red[(g<<7)+l+s]; __syncthreads(); }
    if (l == 0) m4[g] = red[g<<7] / DM_;
    __syncthreads();
    float mu = m4[g];
    float d1 = hv[g][l] - mu;
    float d2 = (l < DM_-128) ? (hv[g][l+128] - mu) : 0.f;
    red[tid] = d1*d1 + d2*d2; __syncthreads();
    for (int s = 64; s > 0; s >>= 1){ if (l < s) red[(g<<7)+l] += red[(g<<7)+l+s]; __syncthreads(); }
    if (l == 0) v4[g] = red[g<<7] / DM_;
    __syncthreads();

    for (int idx = tid; idx < 4*DM_; idx += 512){
        int rr = idx / DM_, j = idx - rr*DM_;
        int r = r0 + rr;
        if (r < 777){
            float* op;
            if (r < 768){ int n = r & 255, v = r >> 8; op = qg + (long)(v*256+n)*DM_; }
            else        { op = sEnc + (long)(r-768)*DM_; }
            op[j] = ln_g[j]*(hv[rr][j]-m4[rr])*rsqrtf(v4[rr]+1e-5f) + ln_b[j];
        }
    }
}

// ---------------------------------------------------------------------------
// Kernel 4: sw (+ sg).  grid = 75, 64 thr.  s = b/25, 64 cols per block.
__global__ __launch_bounds__(64) void sw_kernel(
    const float* __restrict__ sEnc, const float* __restrict__ Whh,
    float* __restrict__ sg, float* __restrict__ sW)
{
    int b = blockIdx.x, tid = threadIdx.x;
    int s = b / 25, c0 = (b - s*25)*64;
    __shared__ float sgl[DM_];
    for (int j = tid; j < DM_; j += 64){
        float val = (sEnc[s*DM_ + j] + sEnc[(3+s)*DM_ + j] + sEnc[(6+s)*DM_ + j]) * (1.f/3.f);
        sgl[j] = val;
        if (c0 == 0) sg[s*DM_ + j] = val;
    }
    __syncthreads();
    int col = c0 + tid;
    float acc = 0.f;
    for (int i = 0; i < DM_; ++i) acc += sgl[i] * Whh[(long)(DM_+i)*G4_ + col];
    sW[s*G4_ + col] = acc;
}

// ---------------------------------------------------------------------------
// Tiled fp32 GEMM: C[768x1600] = A[768x200] @ B[200x1600] + epilogue.
// mode 0: += bih+bhh.  mode 1: += qW0 + alpha·sW.
// tile 32x64, 128 thr (4x4 per thread), K-tiles of 50 (LDS 19.2 KB).
__global__ __launch_bounds__(128) void gemm_kernel(
    const float* __restrict__ A, const float* __restrict__ B,
    const float* __restrict__ qW0, const float* __restrict__ sW,
    const float* __restrict__ alpha,
    const float* __restrict__ bih, const float* __restrict__ bhh,
    float* __restrict__ C, int mode)
{
    int bx = blockIdx.x % 25, by = blockIdx.x / 25;
    int row0 = by*32, col0 = bx*64;
    int tid = threadIdx.x;

    __shared__ float As[50][32];
    __shared__ float Bs[50][64];
    __shared__ float alf[32][3];

    if (mode == 1 && tid < 96) alf[tid/3][tid%3] = alpha[(row0 + tid/3)*3 + tid%3];

    int tx = tid & 15, ty = tid >> 4;
    float acc[4][4] = {};

    for (int kt = 0; kt < 4; ++kt){
        // stage A: 32 rows x 25 float2
        for (int idx = tid; idx < 800; idx += 128){
            int r = idx & 31, p = idx >> 5;
            float2 a2 = *(const float2*)(A + (long)(row0+r)*DM_ + kt*50 + p*2);
            As[p*2][r] = a2.x; As[p*2+1][r] = a2.y;
        }
        // stage B: 50 rows x 16 float4
        for (int idx = tid; idx < 800; idx += 128){
            int k = idx >> 4, c4 = idx & 15;
            *(float4*)(&Bs[k][c4*4]) = *(const float4*)(B + (long)(kt*50+k)*G4_ + col0 + c4*4);
        }
        __syncthreads();
        #pragma unroll 2
        for (int k = 0; k < 50; ++k){
            float4 a = *(const float4*)(&As[k][ty*4]);
            float4 bq = *(const float4*)(&Bs[k][tx*4]);
            acc[0][0]+=a.x*bq.x; acc[0][1]+=a.x*bq.y; acc[0][2]+=a.x*bq.z; acc[0][3]+=a.x*bq.w;
            acc[1][0]+=a.y*bq.x; acc[1][1]+=a.y*bq.y; acc[1][2]+=a.y*bq.z; acc[1][3]+=a.y*bq.w;
            acc[2][0]+=a.z*bq.x; acc[2][1]+=a.z*bq.y; acc[2][2]+=a.z*bq.z; acc[2][3]+=a.z*bq.w;
            acc[3][0]+=a.w*bq.x; acc[3][1]+=a.w*bq.y; acc[3][2]+=a.w*bq.z; acc[3][3]+=a.w*bq.w;
        }
        __syncthreads();
    }

    int cc0 = col0 + tx*4;
    if (mode == 0){
        float4 u = *(const float4*)(bih + cc0);
        float4 w = *(const float4*)(bhh + cc0);
        float4 add = make_float4(u.x+w.x, u.y+w.y, u.z+w.z, u.w+w.w);
        #pragma unroll
        for (int r = 0; r < 4; ++r){
            int row = row0 + ty*4 + r;
            float4 o = make_float4(acc[r][0]+add.x, acc[r][1]+add.y, acc[r][2]+add.z, acc[r][3]+add.w);
            *(float4*)(C + (long)row*G4_ + cc0) = o;
        }
    } else {
        float4 s0 = *(const float4*)(sW + 0*G4_ + cc0);
        float4 s1 = *(const float4*)(sW + 1*G4_ + cc0);
        float4 s2 = *(const float4*)(sW + 2*G4_ + cc0);
        #pragma unroll
        for (int r = 0; r < 4; ++r){
            int row = row0 + ty*4 + r;
            float a0 = alf[ty*4+r][0], a1 = alf[ty*4+r][1], a2 = alf[ty*4+r][2];
            float4 q = *(const float4*)(qW0 + (long)row*G4_ + cc0);
            float4 o;
            o.x = acc[r][0] + q.x + a0*s0.x + a1*s1.x + a2*s2.x;
            o.y = acc[r][1] + q.y + a0*s0.y + a1*s1.y + a2*s2.y;
            o.z = acc[r][2] + q.z + a0*s0.z + a1*s1.z + a2*s2.z;
            o.w = acc[r][3] + q.w + a0*s0.w + a1*s1.w + a2*s2.w;
            *(float4*)(C + (long)row*G4_ + cc0) = o;
        }
    }
}

// ---------------------------------------------------------------------------
// LSTM cell + support attention. grid 192 x 256 thr, 4 rows/block.
__global__ __launch_bounds__(256) void cell_kernel(
    const float* __restrict__ G, const float* __restrict__ qg,
    const float* __restrict__ sg, float* __restrict__ c,
    float* __restrict__ h, float* __restrict__ alpha, float* __restrict__ sAll,
    int first, int last)
{
    int b = blockIdx.x, tid = threadIdx.x;
    int row0 = b*4;
    __shared__ float hbuf[4][DM_];
    __shared__ float sup[600];
    __shared__ float lg[4][3];

    for (int i = tid; i < 600; i += 256) sup[i] = sg[i];

    for (int idx = tid; idx < 4*DI_; idx += 256){
        int r = idx / DI_, j = idx - r*DI_;
        int row = row0 + r;
        const float* g = G + (long)row*G4_;
        float gi = g[j], gf = g[DI_+j], gg = g[2*DI_+j];
        float cold = first ? 0.f : c[(long)row*DI_ + j];
        float c2 = sigf(gf)*cold + sigf(gi)*tanhf(gg);
        c[(long)row*DI_ + j] = c2;
        if (j < DM_){
            float go = g[3*DI_+j];
            float hv = qg[(long)row*DM_ + j] + sigf(go)*tanhf(c2);
            hbuf[r][j] = hv;
            h[(long)row*DM_ + j] = hv;
        }
    }
    __syncthreads();

    if (!last){
        if (tid < 192){
            int p = tid >> 4, l = tid & 15, r = p/3, s = p - r*3;
            float part = 0.f;
            for (int d = l; d < DM_; d += 16) part += hbuf[r][d]*sup[s*DM_+d];
            for (int o = 8; o; o >>= 1) part += __shfl_down(part, o, 16);
            if (!l) lg[r][s] = part;
        }
        __syncthreads();
        if (tid < 4){
            float l0 = lg[tid][0], l1 = lg[tid][1], l2 = lg[tid][2];
            float m = fmaxf(l0, fmaxf(l1, l2));
            float e0 = __expf(l0-m), e1 = __expf(l1-m), e2 = __expf(l2-m);
            float inv = 1.f/(e0+e1+e2);
            alpha[(row0+tid)*3+0] = e0*inv;
            alpha[(row0+tid)*3+1] = e1*inv;
            alpha[(row0+tid)*3+2] = e2*inv;
        }
    } else {
        int v = row0 >> 8;
        if (tid < 64){
            int r = tid >> 4, l = tid & 15;
            float part = 0.f;
            for (int d = l; d < DM_; d += 16) part += hbuf[r][d]*sup[v*DM_+d];
            for (int o = 8; o; o >>= 1) part += __shfl_down(part, o, 16);
            if (!l) sAll[row0+r] = part;
        }
    }
}

// ---------------------------------------------------------------------------
__global__ void final_kernel(const float* __restrict__ sAll, float* __restrict__ out){
    int n = blockIdx.x*blockDim.x + threadIdx.x;
    if (n < 256) out[n] = fmaxf(sAll[n], fmaxf(sAll[256+n], sAll[512+n]));
}

// ---------------------------------------------------------------------------
extern "C" void kernel_launch(void* const* d_in, const int* in_sizes, int n_in,
                              void* d_out, int out_size, void* d_ws, size_t ws_size,
                              hipStream_t stream)
{
    const float* ent_emb=(const float*)d_in[0];
    const float* rel_emb=(const float*)d_in[1];
    const float* W1=(const float*)d_in[2];  const float* b1=(const float*)d_in[3];
    const float* W2=(const float*)d_in[4];  const float* b2=(const float*)d_in[5];
    const float* W3=(const float*)d_in[6];  const float* b3=(const float*)d_in[7];
    const float* attW1=(const float*)d_in[8];
    const float* attW2=(const float*)d_in[10];
    const float* seW1=(const float*)d_in[12]; const float* seb1=(const float*)d_in[13];
    const float* seW2=(const float*)d_in[14]; const float* seb2=(const float*)d_in[15];
    const float* ln_g=(const float*)d_in[16]; const float* ln_b=(const float*)d_in[17];
    const float* Wih=(const float*)d_in[18];  const float* bih=(const float*)d_in[19];
    const float* Whh=(const float*)d_in[20];  const float* bhh=(const float*)d_in[21];
    const int* qlc_out=(const int*)d_in[24];  const int* qlc_in=(const int*)d_in[25];
    const int* qrc_out=(const int*)d_in[27];  const int* qrc_in=(const int*)d_in[28];
    const int* slc_out=(const int*)d_in[30];  const int* slc_in=(const int*)d_in[31];
    const int* src_out=(const int*)d_in[33];  const int* src_in=(const int*)d_in[34];

    float* ws = (float*)d_ws;
    unsigned short* ent_bf = (unsigned short*)ws;  // 1.5M bf16 = 750K float slots (region reserves 1.5M floats)
    float* gates = ws;                 // overlays ent_bf region (disjoint lifetime), 1,228,800 <= 1,500,000
    float* rs_in = ws + 1500000;       // 15,000
    float* rs_out= ws + 1515000;       // 15,000
    float* qn    = ws + 1530000;       // 153,600 (dead after senc -> reused as h)
    float* sn    = ws + 1683600;       // 1,800
    float* qg    = ws + 1685400;       // 153,600
    float* sEnc  = ws + 1839000;       // 1,800
    float* sg    = ws + 1840800;       // 600
    float* qW0   = ws + 1841400;       // 1,228,800
    float* cst   = ws + 3070200;       // 307,200
    float* alpha = ws + 3377400;       // 2,304
    float* sW    = ws + 3379704;       // 4,800
    float* sAll  = ws + 3384504;       // 768
    float* h     = qn;                 // 153,600

    views_kernel<<<1250, 128, 0, stream>>>(ent_emb, rel_emb, W1,b1,W2,b2,W3,b3,
                                           attW1, attW2, ent_bf, rs_in, rs_out);
    neigh_kernel<<<dim3(518,3), 512, 0, stream>>>(qlc_out,qlc_in,qrc_out,qrc_in,
                                                  slc_out,slc_in,src_out,src_in,
                                                  ent_bf, rs_in, rs_out, qn, sn);
    senc_kernel<<<195, 512, 0, stream>>>(qn, sn, seW1,seb1,seW2,seb2, ln_g,ln_b, qg, sEnc);
    sw_kernel<<<75, 64, 0, stream>>>(sEnc, Whh, sg, sW);

    // qW0 = qg @ Wih + bih + bhh
    gemm_kernel<<<600, 128, 0, stream>>>(qg, Wih, nullptr, nullptr, nullptr,
                                         bih, bhh, qW0, 0);
    // step 0: gates = qW0
    cell_kernel<<<192, 256, 0, stream>>>(qW0, qg, sg, cst, h, alpha, sAll, 1, 0);
    // steps 1..3
    for (int s = 1; s < 4; ++s){
        gemm_kernel<<<600, 128, 0, stream>>>(h, Whh, qW0, sW, alpha,
                                             nullptr, nullptr, gates, 1);
        cell_kernel<<<192, 256, 0, stream>>>(gates, qg, sg, cst, h, alpha, sAll,
                                             0, (s==3) ? 1 : 0);
    }
    final_kernel<<<1, 256, 0, stream>>>(sAll, (float*)d_out);
}